// Round 1
// baseline (33300.345 us; speedup 1.0000x reference)
//
#include <hip/hip_runtime.h>
#include <math.h>

// JacobiConv: y = sum_k comb[k] (.) P_k,  P_k = Jacobi recurrence with L @ P matmuls.
// N=16384, C=32, K=10, A=B=1. All fp32.
// Round 1: correct fp32 baseline. GEMM: per-wave 4 rows, lanes slice K;
// P^T in XOR-swizzled LDS (double-buffered); L loads double-buffered in regs.
// Workspace use: 3 ping-pong P buffers (3 * 2 MiB = 6 MiB required).

#define NN 16384
#define CC 32
#define KCH 256
#define NCHUNK (NN / KCH)
#define KPOLY 10

// ---------------------------------------------------------------- GEMM helpers
__device__ __forceinline__ void stage_load(const float* __restrict__ P, int k0, int tid,
                                           float4 pv[8]) {
#pragma unroll
  for (int j = 0; j < 8; ++j) {
    pv[j] = reinterpret_cast<const float4*>(P + (size_t)k0 * CC)[tid + 256 * j];
  }
}

// LDS layout: Pt[c][k ^ (c & 28)] (column-major, XOR swizzle).
// Reads (fixed c, k = 4*lane..): conflict-free b128. Writes: <=2-way (free).
__device__ __forceinline__ void stage_write(float* __restrict__ buf, int tid,
                                            const float4 pv[8]) {
#pragma unroll
  for (int j = 0; j < 8; ++j) {
    int idx = tid + 256 * j;
    int kr = idx >> 3;
    int c0 = (idx & 7) << 2;
    int ks = kr ^ (c0 & 28);  // (c0+m)&28 == c0&28 for m<4
    buf[(c0 + 0) * KCH + ks] = pv[j].x;
    buf[(c0 + 1) * KCH + ks] = pv[j].y;
    buf[(c0 + 2) * KCH + ks] = pv[j].z;
    buf[(c0 + 3) * KCH + ks] = pv[j].w;
  }
}

__device__ __forceinline__ void load_L(const float* __restrict__ Lm, int rowBase, int k0,
                                       int lane, float4 lv[4]) {
#pragma unroll
  for (int r = 0; r < 4; ++r) {
    lv[r] = *reinterpret_cast<const float4*>(Lm + (size_t)(rowBase + r) * NN + k0 + 4 * lane);
  }
}

__device__ __forceinline__ void compute_chunk(const float* __restrict__ buf, int lane,
                                              const float4 lv[4], float acc[4][CC]) {
#pragma unroll
  for (int cg = 0; cg < 8; ++cg) {
    float4 p[4];
#pragma unroll
    for (int cc = 0; cc < 4; ++cc) {
      int c = cg * 4 + cc;
      p[cc] = *reinterpret_cast<const float4*>(buf + c * KCH + ((4 * lane) ^ (c & 28)));
    }
#pragma unroll
    for (int r = 0; r < 4; ++r) {
#pragma unroll
      for (int cc = 0; cc < 4; ++cc) {
        int c = cg * 4 + cc;
        acc[r][c] = fmaf(lv[r].x, p[cc].x, acc[r][c]);
        acc[r][c] = fmaf(lv[r].y, p[cc].y, acc[r][c]);
        acc[r][c] = fmaf(lv[r].z, p[cc].z, acc[r][c]);
        acc[r][c] = fmaf(lv[r].w, p[cc].w, acc[r][c]);
      }
    }
  }
}

// T = L @ P.  Grid: 1024 blocks x 256 threads; block owns 16 output rows.
__global__ __launch_bounds__(256, 2) void gemm_kernel(const float* __restrict__ Lm,
                                                      const float* __restrict__ P,
                                                      float* __restrict__ T) {
  __shared__ float sbuf[2][CC * KCH];  // 2 x 32 KiB
  const int tid = threadIdx.x;
  const int lane = tid & 63;
  const int wave = tid >> 6;
  const int rowBase = blockIdx.x * 16 + wave * 4;

  float acc[4][CC];
#pragma unroll
  for (int r = 0; r < 4; ++r)
#pragma unroll
    for (int c = 0; c < CC; ++c) acc[r][c] = 0.f;

  float4 lvA[4], lvB[4], pv[8];
  stage_load(P, 0, tid, pv);
  load_L(Lm, rowBase, 0, lane, lvA);
  stage_write(sbuf[0], tid, pv);
  __syncthreads();

  for (int ch = 0; ch < NCHUNK; ch += 2) {
    {
      const int kn = (ch + 1) * KCH;  // ch+1 <= 63 always (NCHUNK even)
      stage_load(P, kn, tid, pv);
      load_L(Lm, rowBase, kn, lane, lvB);
      compute_chunk(sbuf[0], lane, lvA, acc);
      stage_write(sbuf[1], tid, pv);
      __syncthreads();
    }
    {
      const bool has = (ch + 2) < NCHUNK;
      if (has) {
        const int kn = (ch + 2) * KCH;
        stage_load(P, kn, tid, pv);
        load_L(Lm, rowBase, kn, lane, lvA);
      }
      compute_chunk(sbuf[1], lane, lvB, acc);
      if (has) stage_write(sbuf[0], tid, pv);
      __syncthreads();
    }
  }

  // butterfly reduce across 64 lanes (all lanes end with full sums)
#pragma unroll
  for (int s = 1; s < 64; s <<= 1) {
#pragma unroll
    for (int r = 0; r < 4; ++r)
#pragma unroll
      for (int c = 0; c < CC; ++c) acc[r][c] += __shfl_xor(acc[r][c], s, 64);
  }
#pragma unroll
  for (int r = 0; r < 4; ++r) {
    if (lane == r) {  // static reg index; one active lane per r
#pragma unroll
      for (int c4 = 0; c4 < CC; c4 += 4) {
        *reinterpret_cast<float4*>(T + (size_t)(rowBase + r) * CC + c4) =
            make_float4(acc[r][c4], acc[r][c4 + 1], acc[r][c4 + 2], acc[r][c4 + 3]);
      }
    }
  }
}

// ---------------------------------------------------------------- elementwise
__global__ void init_y(const float* __restrict__ x, const float* __restrict__ comb,
                       float* __restrict__ y) {
  int idx = blockIdx.x * blockDim.x + threadIdx.x;  // float4 index over N*C/4
  float4 xv = reinterpret_cast<const float4*>(x)[idx];
  int c4 = (idx & 7) << 2;
  float4 cb = *reinterpret_cast<const float4*>(comb + c4);  // comb row 0
  reinterpret_cast<float4*>(y)[idx] =
      make_float4(xv.x * cb.x, xv.y * cb.y, xv.z * cb.z, xv.w * cb.w);
}

// T (in: L@Pprev) -> Pnew (in place); y += comb_row (.) Pnew
__global__ void poly_update(float* __restrict__ T, const float* __restrict__ Pprev,
                            const float* __restrict__ Pprev2, float* __restrict__ y,
                            const float* __restrict__ conv, const float* __restrict__ comb_row,
                            float r1, float r2, float r3, int ia, int ib, int has2) {
  int idx = blockIdx.x * blockDim.x + threadIdx.x;
  float a1 = 2.f * tanhf(conv[ia]);
  float cL = a1 * r1;
  float cP = a1 * r2;
  float4 t = reinterpret_cast<float4*>(T)[idx];
  float4 pp = reinterpret_cast<const float4*>(Pprev)[idx];
  float4 pn;
  pn.x = cL * t.x + cP * pp.x;
  pn.y = cL * t.y + cP * pp.y;
  pn.z = cL * t.z + cP * pp.z;
  pn.w = cL * t.w + cP * pp.w;
  if (has2) {
    float a2 = 2.f * tanhf(conv[ib]);
    float cPP = a1 * a2 * r3;
    float4 p2 = reinterpret_cast<const float4*>(Pprev2)[idx];
    pn.x -= cPP * p2.x;
    pn.y -= cPP * p2.y;
    pn.z -= cPP * p2.z;
    pn.w -= cPP * p2.w;
  }
  reinterpret_cast<float4*>(T)[idx] = pn;
  int c4 = (idx & 7) << 2;
  float4 cb = *reinterpret_cast<const float4*>(comb_row + c4);
  float4 yv = reinterpret_cast<float4*>(y)[idx];
  yv.x = fmaf(cb.x, pn.x, yv.x);
  yv.y = fmaf(cb.y, pn.y, yv.y);
  yv.z = fmaf(cb.z, pn.z, yv.z);
  yv.w = fmaf(cb.w, pn.w, yv.w);
  reinterpret_cast<float4*>(y)[idx] = yv;
}

// ---------------------------------------------------------------- host side
static void jacobi_r(int i, double a, double b, float& r1, float& r2, float& r3) {
  double div = 2.0 * i * (i + a + b) * (2.0 * i + a + b - 2.0);
  r1 = (float)((2.0 * i + a + b) * (2.0 * i + a + b - 1.0) * (2.0 * i + a + b - 2.0) / div);
  r2 = (float)((2.0 * i + a + b - 1.0) * (a * a - b * b) / div);
  r3 = (float)(2.0 * (i + a - 1.0) * (i + b - 1.0) * (2.0 * i + a + b) / div);
}

extern "C" void kernel_launch(void* const* d_in, const int* in_sizes, int n_in,
                              void* d_out, int out_size, void* d_ws, size_t ws_size,
                              hipStream_t stream) {
  const float* x = (const float*)d_in[0];
  const float* Lm = (const float*)d_in[1];
  const float* conv = (const float*)d_in[2];
  const float* comb = (const float*)d_in[3];
  float* y = (float*)d_out;
  float* ws = (float*)d_ws;

  const size_t NC = (size_t)NN * CC;
  float* bufs[3] = {ws, ws + NC, ws + 2 * NC};  // needs 6 MiB of ws

  const double Aj = 1.0, Bj = 1.0;
  const int ew_blocks = (int)(NC / 4 / 256);  // 512

  init_y<<<512, 256, 0, stream>>>(x, comb, y);

  const float* Pprev = x;
  const float* Pprev2 = x;  // unused for i==1
  for (int i = 1; i <= KPOLY; ++i) {
    float* T = bufs[(i - 1) % 3];
    gemm_kernel<<<NN / 16, 256, 0, stream>>>(Lm, Pprev, T);

    float r1, r2, r3;
    if (i == 1) {
      r1 = (float)((Aj + Bj + 2.0) / 2.0);
      r2 = (float)((Aj - Bj) / 2.0);
      r3 = 0.f;
    } else {
      jacobi_r(i, Aj, Bj, r1, r2, r3);
    }
    poly_update<<<ew_blocks, 256, 0, stream>>>(T, Pprev, Pprev2, y, conv,
                                               comb + (size_t)i * CC, r1, r2, r3,
                                               i - 1, (i >= 2) ? i - 2 : 0,
                                               (i >= 2) ? 1 : 0);
    Pprev2 = Pprev;
    Pprev = T;
  }
}

// Round 2
// 3650.041 us; speedup vs baseline: 9.1233x; 9.1233x over previous
//
#include <hip/hip_runtime.h>
#include <math.h>

// JacobiConv: y = sum_k comb[k] (.) P_k,  P_k = Jacobi recurrence with L @ P matmuls.
// N=16384, C=32, K=10, A=B=1. All fp32.
// Round 2: fix register spill. acc[4][16] per lane (col-split halves),
// P staged to LDS via global_load_lds with source-side XOR quad swizzle
// (conflict-free b128 compute reads), L regs ping-ponged, KCH=128 double buffer.

#define NN 16384
#define CC 32
#define KCH 128
#define NCHUNK (NN / KCH)
#define KPOLY 10

__device__ __forceinline__ void async_copy16(float* lds, const float* g) {
  __builtin_amdgcn_global_load_lds(
      (const __attribute__((address_space(1))) unsigned int*)(g),
      (__attribute__((address_space(3))) unsigned int*)(lds), 16, 0, 0);
}

// Stage one wave's quota (32 rows = 4 KiB) of the P tile [kbase..kbase+KCH) into LDS.
// LDS layout: tile[k][Q] (float4 quads) holds P[kbase+k][4*(Q ^ s(k))..], s(k)=(k>>2)&7
// (global k; kbase is a multiple of KCH so s depends only on global k bits).
__device__ __forceinline__ void stage_chunk(float* __restrict__ dst,
                                            const float* __restrict__ P, int kbase,
                                            int wave, int sd, int sq) {
#pragma unroll
  for (int t = 0; t < 4; ++t) {
    const int krow = wave * 32 + t * 8;       // local row base (multiple of 8)
    const int k = kbase + krow + sd;          // global P row this lane reads
    const int s = (k >> 2) & 7;
    const float* src = P + (size_t)k * CC + 4 * (sq ^ s);
    async_copy16(dst + (size_t)krow * CC, src);
  }
}

__device__ __forceinline__ void load_lv(float4 lv[4], const float* __restrict__ Lm,
                                        int rowBase, int kofs) {
#pragma unroll
  for (int r = 0; r < 4; ++r) {
    lv[r] = *reinterpret_cast<const float4*>(Lm + (size_t)(rowBase + r) * NN + kofs);
  }
}

// Consume one K-chunk: lane (ks, ch) covers k = 4*ks..4*ks+3, cols 16*ch..16*ch+15.
__device__ __forceinline__ void compute_chunk(const float* __restrict__ buf, int ks, int ch,
                                              const float4 lv[4], float acc[4][16]) {
  const int qlo = ks & 3;
  const float* bp = buf + 128 * ks + (((ch ^ ((ks >> 2) & 1))) << 4);
#pragma unroll
  for (int m = 0; m < 4; ++m) {
#pragma unroll
    for (int qq = 0; qq < 4; ++qq) {
      const float4 p = *reinterpret_cast<const float4*>(bp + 32 * m + 4 * (qq ^ qlo));
#pragma unroll
      for (int r = 0; r < 4; ++r) {
        const float lm = (m == 0) ? lv[r].x : (m == 1) ? lv[r].y : (m == 2) ? lv[r].z : lv[r].w;
        acc[r][4 * qq + 0] = fmaf(lm, p.x, acc[r][4 * qq + 0]);
        acc[r][4 * qq + 1] = fmaf(lm, p.y, acc[r][4 * qq + 1]);
        acc[r][4 * qq + 2] = fmaf(lm, p.z, acc[r][4 * qq + 2]);
        acc[r][4 * qq + 3] = fmaf(lm, p.w, acc[r][4 * qq + 3]);
      }
    }
  }
}

// T = L @ P. Grid: 1024 blocks x 256 threads; block owns 16 rows (4 per wave).
__global__ __launch_bounds__(256, 2) void gemm_kernel(const float* __restrict__ Lm,
                                                      const float* __restrict__ P,
                                                      float* __restrict__ T) {
  __shared__ float sbuf[2][KCH * CC];  // 2 x 16 KiB
  const int tid = threadIdx.x;
  const int lane = tid & 63;
  const int wave = tid >> 6;
  const int ks = lane & 31;   // k-slot (k = 4*ks + m)
  const int ch = lane >> 5;   // column half
  const int sd = lane >> 3;   // staging: row within 8-row block
  const int sq = lane & 7;    // staging: quad
  const int rowBase = blockIdx.x * 16 + wave * 4;

  float acc[4][16];
#pragma unroll
  for (int r = 0; r < 4; ++r)
#pragma unroll
    for (int c = 0; c < 16; ++c) acc[r][c] = 0.f;

  float4 lvA[4], lvB[4];
  stage_chunk(sbuf[0], P, 0, wave, sd, sq);
  load_lv(lvA, Lm, rowBase, 4 * ks);
  __syncthreads();  // drains vmcnt: sbuf[0] + lvA ready

  for (int t = 0; t < NCHUNK; t += 2) {
    {  // even: compute sbuf[0]/lvA, prefetch into sbuf[1]/lvB
      const int kn = (t + 1) * KCH;  // t+1 < NCHUNK always (NCHUNK even)
      stage_chunk(sbuf[1], P, kn, wave, sd, sq);
      load_lv(lvB, Lm, rowBase, kn + 4 * ks);
      compute_chunk(sbuf[0], ks, ch, lvA, acc);
      __syncthreads();
    }
    {  // odd: compute sbuf[1]/lvB, prefetch into sbuf[0]/lvA
      const bool has = (t + 2) < NCHUNK;
      if (has) {
        const int kn = (t + 2) * KCH;
        stage_chunk(sbuf[0], P, kn, wave, sd, sq);
        load_lv(lvA, Lm, rowBase, kn + 4 * ks);
      }
      compute_chunk(sbuf[1], ks, ch, lvB, acc);
      __syncthreads();
    }
  }

  // reduce across the 32 k-slots within each column-half (5-stage butterfly)
#pragma unroll
  for (int s = 1; s < 32; s <<= 1) {
#pragma unroll
    for (int r = 0; r < 4; ++r)
#pragma unroll
      for (int c = 0; c < 16; ++c) acc[r][c] += __shfl_xor(acc[r][c], s, 64);
  }
#pragma unroll
  for (int r = 0; r < 4; ++r) {
    if (ks == r) {  // lanes r and 32+r write row r (their col half)
#pragma unroll
      for (int q = 0; q < 4; ++q) {
        *reinterpret_cast<float4*>(T + (size_t)(rowBase + r) * CC + 16 * ch + 4 * q) =
            make_float4(acc[r][4 * q], acc[r][4 * q + 1], acc[r][4 * q + 2], acc[r][4 * q + 3]);
      }
    }
  }
}

// ---------------------------------------------------------------- elementwise
__global__ void init_y(const float* __restrict__ x, const float* __restrict__ comb,
                       float* __restrict__ y) {
  int idx = blockIdx.x * blockDim.x + threadIdx.x;  // float4 index over N*C/4
  float4 xv = reinterpret_cast<const float4*>(x)[idx];
  int c4 = (idx & 7) << 2;
  float4 cb = *reinterpret_cast<const float4*>(comb + c4);  // comb row 0
  reinterpret_cast<float4*>(y)[idx] =
      make_float4(xv.x * cb.x, xv.y * cb.y, xv.z * cb.z, xv.w * cb.w);
}

// T (in: L@Pprev) -> Pnew (in place); y += comb_row (.) Pnew
__global__ void poly_update(float* __restrict__ T, const float* __restrict__ Pprev,
                            const float* __restrict__ Pprev2, float* __restrict__ y,
                            const float* __restrict__ conv, const float* __restrict__ comb_row,
                            float r1, float r2, float r3, int ia, int ib, int has2) {
  int idx = blockIdx.x * blockDim.x + threadIdx.x;
  float a1 = 2.f * tanhf(conv[ia]);
  float cL = a1 * r1;
  float cP = a1 * r2;
  float4 t = reinterpret_cast<float4*>(T)[idx];
  float4 pp = reinterpret_cast<const float4*>(Pprev)[idx];
  float4 pn;
  pn.x = cL * t.x + cP * pp.x;
  pn.y = cL * t.y + cP * pp.y;
  pn.z = cL * t.z + cP * pp.z;
  pn.w = cL * t.w + cP * pp.w;
  if (has2) {
    float a2 = 2.f * tanhf(conv[ib]);
    float cPP = a1 * a2 * r3;
    float4 p2 = reinterpret_cast<const float4*>(Pprev2)[idx];
    pn.x -= cPP * p2.x;
    pn.y -= cPP * p2.y;
    pn.z -= cPP * p2.z;
    pn.w -= cPP * p2.w;
  }
  reinterpret_cast<float4*>(T)[idx] = pn;
  int c4 = (idx & 7) << 2;
  float4 cb = *reinterpret_cast<const float4*>(comb_row + c4);
  float4 yv = reinterpret_cast<float4*>(y)[idx];
  yv.x = fmaf(cb.x, pn.x, yv.x);
  yv.y = fmaf(cb.y, pn.y, yv.y);
  yv.z = fmaf(cb.z, pn.z, yv.z);
  yv.w = fmaf(cb.w, pn.w, yv.w);
  reinterpret_cast<float4*>(y)[idx] = yv;
}

// ---------------------------------------------------------------- host side
static void jacobi_r(int i, double a, double b, float& r1, float& r2, float& r3) {
  double div = 2.0 * i * (i + a + b) * (2.0 * i + a + b - 2.0);
  r1 = (float)((2.0 * i + a + b) * (2.0 * i + a + b - 1.0) * (2.0 * i + a + b - 2.0) / div);
  r2 = (float)((2.0 * i + a + b - 1.0) * (a * a - b * b) / div);
  r3 = (float)(2.0 * (i + a - 1.0) * (i + b - 1.0) * (2.0 * i + a + b) / div);
}

extern "C" void kernel_launch(void* const* d_in, const int* in_sizes, int n_in,
                              void* d_out, int out_size, void* d_ws, size_t ws_size,
                              hipStream_t stream) {
  const float* x = (const float*)d_in[0];
  const float* Lm = (const float*)d_in[1];
  const float* conv = (const float*)d_in[2];
  const float* comb = (const float*)d_in[3];
  float* y = (float*)d_out;
  float* ws = (float*)d_ws;

  const size_t NC = (size_t)NN * CC;
  float* bufs[3] = {ws, ws + NC, ws + 2 * NC};  // needs 6 MiB of ws

  const double Aj = 1.0, Bj = 1.0;
  const int ew_blocks = (int)(NC / 4 / 256);  // 512

  init_y<<<512, 256, 0, stream>>>(x, comb, y);

  const float* Pprev = x;
  const float* Pprev2 = x;  // unused for i==1
  for (int i = 1; i <= KPOLY; ++i) {
    float* T = bufs[(i - 1) % 3];
    gemm_kernel<<<NN / 16, 256, 0, stream>>>(Lm, Pprev, T);

    float r1, r2, r3;
    if (i == 1) {
      r1 = (float)((Aj + Bj + 2.0) / 2.0);
      r2 = (float)((Aj - Bj) / 2.0);
      r3 = 0.f;
    } else {
      jacobi_r(i, Aj, Bj, r1, r2, r3);
    }
    poly_update<<<ew_blocks, 256, 0, stream>>>(T, Pprev, Pprev2, y, conv,
                                               comb + (size_t)i * CC, r1, r2, r3,
                                               i - 1, (i >= 2) ? i - 2 : 0,
                                               (i >= 2) ? 1 : 0);
    Pprev2 = Pprev;
    Pprev = T;
  }
}

// Round 3
// 1652.229 us; speedup vs baseline: 20.1548x; 2.2092x over previous
//
#include <hip/hip_runtime.h>
#include <math.h>

// JacobiConv: y = sum_k comb[k] (.) P_k,  P_k = Jacobi recurrence with L @ P matmuls.
// N=16384, C=32, K=10, A=B=1.
// Round 3: fp16 MFMA GEMM. L converted to fp16 once per call; 10 GEMMs stream
// Lh (0.5 GiB) HBM-bound with mfma_f32_16x16x32_f16, fp32 accumulate.
// Split-K=16 with fp32 partials; reduction fused into poly_update.
// Masters (P ring, y) stay fp32. B operand kept in blocked layout Ph[kb][c][8].

#define NN 16384
#define CC 32
#define KPOLY 10
#define NSPLIT 16
#define KSEG (NN / NSPLIT)   // 1024
#define STEPS (KSEG / 32)    // 32

typedef _Float16 half8 __attribute__((ext_vector_type(8)));
typedef float f32x4 __attribute__((ext_vector_type(4)));

union U16 {
  uint4 u;
  half8 h;
};
union H4 {
  _Float16 h[4];
  uint2 u;
};

// ------------------------------------------------------------- L fp32 -> fp16
__global__ __launch_bounds__(256) void conv_L(const float* __restrict__ L,
                                              _Float16* __restrict__ Lh) {
  const size_t nquads = (size_t)NN * NN / 4;  // 67108864
  const size_t stride = (size_t)gridDim.x * blockDim.x;
  for (size_t idx = blockIdx.x * blockDim.x + threadIdx.x; idx < nquads; idx += stride) {
    float4 v = reinterpret_cast<const float4*>(L)[idx];
    H4 o;
    o.h[0] = (_Float16)v.x;
    o.h[1] = (_Float16)v.y;
    o.h[2] = (_Float16)v.z;
    o.h[3] = (_Float16)v.w;
    reinterpret_cast<uint2*>(Lh)[idx] = o.u;
  }
}

// ------------------------------------------------------------- f16 MFMA GEMM
// part[split][n][c] = sum over k-seg of L[n][k] * P[k][c]
// Grid: 1024 blocks x 256 threads. Block = 4 waves; wave owns 64 rows, one k-seg.
__global__ __launch_bounds__(256, 4) void gemm_f16(const _Float16* __restrict__ Lh,
                                                   const _Float16* __restrict__ Ph,
                                                   float* __restrict__ part) {
  const int tid = threadIdx.x;
  const int lane = tid & 63;
  const int wave = tid >> 6;
  const int rg = blockIdx.x & 63;
  const int split = blockIdx.x >> 6;
  const int rb = rg * 256 + wave * 64;
  const int k0 = split * KSEG;
  const int l15 = lane & 15;
  const int lg = lane >> 4;

  const _Float16* Ap[4];
#pragma unroll
  for (int rt = 0; rt < 4; ++rt)
    Ap[rt] = Lh + (size_t)(rb + rt * 16 + l15) * NN + k0 + 8 * lg;
  const _Float16* Bp[2];
#pragma unroll
  for (int ct = 0; ct < 2; ++ct)
    Bp[ct] = Ph + (size_t)(k0 / 8 + lg) * 256 + (size_t)(ct * 16 + l15) * 8;

  f32x4 acc[4][2];
#pragma unroll
  for (int rt = 0; rt < 4; ++rt)
#pragma unroll
    for (int ct = 0; ct < 2; ++ct) acc[rt][ct] = (f32x4){0.f, 0.f, 0.f, 0.f};

  U16 A[2][4], B[2][2];
#pragma unroll
  for (int rt = 0; rt < 4; ++rt) A[0][rt].u = *reinterpret_cast<const uint4*>(Ap[rt]);
#pragma unroll
  for (int ct = 0; ct < 2; ++ct) B[0][ct].u = *reinterpret_cast<const uint4*>(Bp[ct]);

#pragma unroll
  for (int kk = 0; kk < STEPS; ++kk) {
    const int cur = kk & 1;
    const int nxt = cur ^ 1;
    if (kk < STEPS - 1) {
#pragma unroll
      for (int rt = 0; rt < 4; ++rt)
        A[nxt][rt].u = *reinterpret_cast<const uint4*>(Ap[rt] + 32 * (kk + 1));
#pragma unroll
      for (int ct = 0; ct < 2; ++ct)
        B[nxt][ct].u = *reinterpret_cast<const uint4*>(Bp[ct] + 1024 * (kk + 1));
    }
#pragma unroll
    for (int rt = 0; rt < 4; ++rt)
#pragma unroll
      for (int ct = 0; ct < 2; ++ct)
        acc[rt][ct] = __builtin_amdgcn_mfma_f32_16x16x32_f16(A[cur][rt].h, B[cur][ct].h,
                                                             acc[rt][ct], 0, 0, 0);
  }

  float* pb = part + (size_t)split * NN * CC;
#pragma unroll
  for (int rt = 0; rt < 4; ++rt)
#pragma unroll
    for (int ct = 0; ct < 2; ++ct)
#pragma unroll
      for (int j = 0; j < 4; ++j)
        pb[(size_t)(rb + rt * 16 + lg * 4 + j) * CC + ct * 16 + l15] = acc[rt][ct][j];
}

// ---------------------------------------------------------------- elementwise
// y = comb0 (.) x ; Ph_blk = fp16(x)
__global__ __launch_bounds__(256) void init_kernel(const float* __restrict__ x,
                                                   const float* __restrict__ comb,
                                                   float* __restrict__ y,
                                                   _Float16* __restrict__ Ph) {
  int idx = blockIdx.x * blockDim.x + threadIdx.x;  // float4 index over N*C/4
  float4 xv = reinterpret_cast<const float4*>(x)[idx];
  int c4 = (idx & 7) << 2;
  int n = idx >> 3;
  float4 cb = *reinterpret_cast<const float4*>(comb + c4);
  reinterpret_cast<float4*>(y)[idx] =
      make_float4(xv.x * cb.x, xv.y * cb.y, xv.z * cb.z, xv.w * cb.w);
  size_t pb = (size_t)(n >> 3) * 256 + (size_t)c4 * 8 + (n & 7);
  Ph[pb] = (_Float16)xv.x;
  Ph[pb + 8] = (_Float16)xv.y;
  Ph[pb + 16] = (_Float16)xv.z;
  Ph[pb + 24] = (_Float16)xv.w;
}

// t = sum_s part[s]; Pnew = cL*t + cP*Pprev - cPP*Pprev2; y += comb (.) Pnew;
// Ph_blk = fp16(Pnew)
__global__ __launch_bounds__(256) void poly_update(
    const float* __restrict__ part, float* __restrict__ Pnew,
    const float* __restrict__ Pprev, const float* __restrict__ Pprev2,
    float* __restrict__ y, _Float16* __restrict__ Ph, const float* __restrict__ conv,
    const float* __restrict__ comb_row, float r1, float r2, float r3, int ia, int ib,
    int has2) {
  int idx = blockIdx.x * blockDim.x + threadIdx.x;
  float a1 = 2.f * tanhf(conv[ia]);
  float cL = a1 * r1;
  float cP = a1 * r2;

  float4 t = make_float4(0.f, 0.f, 0.f, 0.f);
#pragma unroll
  for (int s = 0; s < NSPLIT; ++s) {
    float4 p = reinterpret_cast<const float4*>(part)[(size_t)s * (NN * CC / 4) + idx];
    t.x += p.x;
    t.y += p.y;
    t.z += p.z;
    t.w += p.w;
  }

  float4 pp = reinterpret_cast<const float4*>(Pprev)[idx];
  float4 pn;
  pn.x = cL * t.x + cP * pp.x;
  pn.y = cL * t.y + cP * pp.y;
  pn.z = cL * t.z + cP * pp.z;
  pn.w = cL * t.w + cP * pp.w;
  if (has2) {
    float a2 = 2.f * tanhf(conv[ib]);
    float cPP = a1 * a2 * r3;
    float4 p2 = reinterpret_cast<const float4*>(Pprev2)[idx];
    pn.x -= cPP * p2.x;
    pn.y -= cPP * p2.y;
    pn.z -= cPP * p2.z;
    pn.w -= cPP * p2.w;
  }
  reinterpret_cast<float4*>(Pnew)[idx] = pn;

  int c4 = (idx & 7) << 2;
  int n = idx >> 3;
  size_t pb = (size_t)(n >> 3) * 256 + (size_t)c4 * 8 + (n & 7);
  Ph[pb] = (_Float16)pn.x;
  Ph[pb + 8] = (_Float16)pn.y;
  Ph[pb + 16] = (_Float16)pn.z;
  Ph[pb + 24] = (_Float16)pn.w;

  float4 cb = *reinterpret_cast<const float4*>(comb_row + c4);
  float4 yv = reinterpret_cast<float4*>(y)[idx];
  yv.x = fmaf(cb.x, pn.x, yv.x);
  yv.y = fmaf(cb.y, pn.y, yv.y);
  yv.z = fmaf(cb.z, pn.z, yv.z);
  yv.w = fmaf(cb.w, pn.w, yv.w);
  reinterpret_cast<float4*>(y)[idx] = yv;
}

// ---------------------------------------------------------------- host side
static void jacobi_r(int i, double a, double b, float& r1, float& r2, float& r3) {
  double div = 2.0 * i * (i + a + b) * (2.0 * i + a + b - 2.0);
  r1 = (float)((2.0 * i + a + b) * (2.0 * i + a + b - 1.0) * (2.0 * i + a + b - 2.0) / div);
  r2 = (float)((2.0 * i + a + b - 1.0) * (a * a - b * b) / div);
  r3 = (float)(2.0 * (i + a - 1.0) * (i + b - 1.0) * (2.0 * i + a + b) / div);
}

extern "C" void kernel_launch(void* const* d_in, const int* in_sizes, int n_in,
                              void* d_out, int out_size, void* d_ws, size_t ws_size,
                              hipStream_t stream) {
  const float* x = (const float*)d_in[0];
  const float* Lm = (const float*)d_in[1];
  const float* conv = (const float*)d_in[2];
  const float* comb = (const float*)d_in[3];
  float* y = (float*)d_out;
  char* ws = (char*)d_ws;

  // workspace layout (bytes)
  _Float16* Lh = (_Float16*)ws;                               // 512 MiB
  float* part = (float*)(ws + 536870912ull);                  // 32 MiB
  _Float16* Ph = (_Float16*)(ws + 536870912ull + 33554432ull);  // 1 MiB (+pad)
  float* Pb0 = (float*)(ws + 536870912ull + 33554432ull + 2097152ull);
  float* Pb1 = Pb0 + (size_t)NN * CC;
  float* Pb2 = Pb1 + (size_t)NN * CC;
  float* bufs[3] = {Pb0, Pb1, Pb2};

  const double Aj = 1.0, Bj = 1.0;
  const int ew_blocks = NN * CC / 4 / 256;  // 512

  conv_L<<<2048, 256, 0, stream>>>(Lm, Lh);
  init_kernel<<<ew_blocks, 256, 0, stream>>>(x, comb, y, Ph);

  const float* Pprev = x;
  const float* Pprev2 = x;  // unused for i==1
  for (int i = 1; i <= KPOLY; ++i) {
    gemm_f16<<<64 * NSPLIT, 256, 0, stream>>>(Lh, Ph, part);

    float r1, r2, r3;
    if (i == 1) {
      r1 = (float)((Aj + Bj + 2.0) / 2.0);
      r2 = (float)((Aj - Bj) / 2.0);
      r3 = 0.f;
    } else {
      jacobi_r(i, Aj, Bj, r1, r2, r3);
    }
    float* Pn = bufs[(i - 1) % 3];
    poly_update<<<ew_blocks, 256, 0, stream>>>(part, Pn, Pprev, Pprev2, y, Ph, conv,
                                               comb + (size_t)i * CC, r1, r2, r3, i - 1,
                                               (i >= 2) ? i - 2 : 0, (i >= 2) ? 1 : 0);
    Pprev2 = Pprev;
    Pprev = Pn;
  }
}

// Round 5
// 1379.521 us; speedup vs baseline: 24.1391x; 1.1977x over previous
//
#include <hip/hip_runtime.h>
#include <math.h>

// JacobiConv: y = sum_k comb[k] (.) P_k,  P_k = Jacobi recurrence with L @ P matmuls.
// N=16384, C=32, K=10, A=B=1.
// Round 5: fragment-packed fp16 L (round-4 fix: nontemporal builtins need native
// ext_vector types, not HIP uint4). conv_L_pack converts L fp32 -> Lf fp16 in MFMA
// fragment-blocked layout (LDS-transposed, coalesced both sides), so every GEMM
// A-load is a contiguous 1 KB wave transaction (sequential streaming, ~fill-rate BW).
// GEMM: mfma_f32_16x16x32_f16, split-K=16, fp32 partials reduced in poly_update.

#define NN 16384
#define CC 32
#define KPOLY 10
#define NSPLIT 16
#define KSEG (NN / NSPLIT)   // 1024
#define STEPS (KSEG / 32)    // 32
#define NTK (NN / 32)        // 512 k-tiles per row-block

typedef _Float16 half8 __attribute__((ext_vector_type(8)));
typedef float f32x4 __attribute__((ext_vector_type(4)));
typedef unsigned int u32x4 __attribute__((ext_vector_type(4)));
typedef unsigned int u32x2 __attribute__((ext_vector_type(2)));

union U16 {
  u32x4 u;
  half8 h;
};
union H4 {
  _Float16 h[4];
  u32x2 u;
};

// ---------------------------------------------------- L fp32 -> fp16 fragment pack
// Lf layout: Lf[((tr*NTK + tk)*64 + lane)*8 + pos] =
//            L[tr*16 + (lane&15)][tk*32 + (lane>>4)*8 + pos]
// Block: 16 rows x 1024 cols slab. Phase 1: coalesced fp32 read -> swizzled LDS.
// Phase 2: per-lane 16B LDS gather (conflict-free) -> coalesced 1KB/wave write.
__global__ __launch_bounds__(256) void conv_L_pack(const float* __restrict__ L,
                                                   _Float16* __restrict__ Lf) {
  __shared__ _Float16 lds[16 * 1024];  // 32 KiB; 16B-unit swizzle u ^= (r&7)
  const int tid = threadIdx.x;
  const int tr = blockIdx.x >> 4;  // row-block 0..1023
  const int sc = blockIdx.x & 15;  // col-slab 0..15 (1024 cols each)
  const float* src = L + (size_t)tr * 16 * NN + (size_t)sc * 1024;

#pragma unroll
  for (int j = 0; j < 16; ++j) {
    const int flat = j * 256 + tid;  // 0..4095
    const int r = flat >> 8;         // row 0..15
    const int cu = flat & 255;       // float4 index within row
    f32x4 v = __builtin_nontemporal_load(
        reinterpret_cast<const f32x4*>(src + (size_t)r * NN) + cu);
    H4 o;
    o.h[0] = (_Float16)v.x;
    o.h[1] = (_Float16)v.y;
    o.h[2] = (_Float16)v.z;
    o.h[3] = (_Float16)v.w;
    const int u = (cu >> 1) ^ (r & 7);
    *reinterpret_cast<u32x2*>(&lds[r * 1024 + u * 8 + (cu & 1) * 4]) = o.u;
  }
  __syncthreads();

  const int lane = tid & 63;
  const int wave = tid >> 6;
  const int r = lane & 15;
  const int lg = lane >> 4;
#pragma unroll
  for (int i = 0; i < 8; ++i) {
    const int tkl = wave * 8 + i;  // tile within slab 0..31
    const int u = (tkl * 4 + lg) ^ (r & 7);
    u32x4 val = *reinterpret_cast<const u32x4*>(&lds[r * 1024 + u * 8]);
    const size_t tk = (size_t)sc * 32 + tkl;
    __builtin_nontemporal_store(
        val, reinterpret_cast<u32x4*>(Lf + ((size_t)tr * NTK + tk) * 512) + lane);
  }
}

// ------------------------------------------------------------- f16 MFMA GEMM
// part[split][n][c] = sum over k-seg of L[n][k] * P[k][c]
// Grid: 1024 blocks x 256 threads. Block = 4 waves; wave owns 64 rows, one k-seg.
__global__ __launch_bounds__(256, 4) void gemm_f16(const _Float16* __restrict__ Lf,
                                                   const _Float16* __restrict__ Ph,
                                                   float* __restrict__ part) {
  const int tid = threadIdx.x;
  const int lane = tid & 63;
  const int wave = tid >> 6;
  const int rg = blockIdx.x & 63;
  const int split = blockIdx.x >> 6;
  const int rb = rg * 256 + wave * 64;
  const int k0 = split * KSEG;
  const int tk0 = k0 >> 5;
  const int l15 = lane & 15;
  const int lg = lane >> 4;

  const u32x4* Ap[4];
#pragma unroll
  for (int rt = 0; rt < 4; ++rt)
    Ap[rt] = reinterpret_cast<const u32x4*>(
                 Lf + ((size_t)((rb >> 4) + rt) * NTK + tk0) * 512) +
             lane;
  const u32x4* Bp[2];
#pragma unroll
  for (int ct = 0; ct < 2; ++ct)
    Bp[ct] = reinterpret_cast<const u32x4*>(Ph + (size_t)(k0 / 8 + lg) * 256 +
                                            (size_t)(ct * 16 + l15) * 8);

  f32x4 acc[4][2];
#pragma unroll
  for (int rt = 0; rt < 4; ++rt)
#pragma unroll
    for (int ct = 0; ct < 2; ++ct) acc[rt][ct] = (f32x4){0.f, 0.f, 0.f, 0.f};

  U16 A[2][4], B[2][2];
#pragma unroll
  for (int rt = 0; rt < 4; ++rt) A[0][rt].u = __builtin_nontemporal_load(Ap[rt]);
#pragma unroll
  for (int ct = 0; ct < 2; ++ct) B[0][ct].u = *Bp[ct];

#pragma unroll
  for (int kk = 0; kk < STEPS; ++kk) {
    const int cur = kk & 1;
    const int nxt = cur ^ 1;
    if (kk < STEPS - 1) {
#pragma unroll
      for (int rt = 0; rt < 4; ++rt)
        A[nxt][rt].u = __builtin_nontemporal_load(Ap[rt] + (kk + 1) * 64);
#pragma unroll
      for (int ct = 0; ct < 2; ++ct)
        B[nxt][ct].u = *reinterpret_cast<const u32x4*>(
            reinterpret_cast<const _Float16*>(Bp[ct]) + 1024 * (kk + 1));
    }
#pragma unroll
    for (int rt = 0; rt < 4; ++rt)
#pragma unroll
      for (int ct = 0; ct < 2; ++ct)
        acc[rt][ct] = __builtin_amdgcn_mfma_f32_16x16x32_f16(A[cur][rt].h, B[cur][ct].h,
                                                             acc[rt][ct], 0, 0, 0);
  }

  float* pb = part + (size_t)split * NN * CC;
#pragma unroll
  for (int rt = 0; rt < 4; ++rt)
#pragma unroll
    for (int ct = 0; ct < 2; ++ct)
#pragma unroll
      for (int j = 0; j < 4; ++j)
        pb[(size_t)(rb + rt * 16 + lg * 4 + j) * CC + ct * 16 + l15] = acc[rt][ct][j];
}

// ---------------------------------------------------------------- elementwise
// y = comb0 (.) x ; Ph_blk = fp16(x)
__global__ __launch_bounds__(256) void init_kernel(const float* __restrict__ x,
                                                   const float* __restrict__ comb,
                                                   float* __restrict__ y,
                                                   _Float16* __restrict__ Ph) {
  int idx = blockIdx.x * blockDim.x + threadIdx.x;  // float4 index over N*C/4
  float4 xv = reinterpret_cast<const float4*>(x)[idx];
  int c4 = (idx & 7) << 2;
  int n = idx >> 3;
  float4 cb = *reinterpret_cast<const float4*>(comb + c4);
  reinterpret_cast<float4*>(y)[idx] =
      make_float4(xv.x * cb.x, xv.y * cb.y, xv.z * cb.z, xv.w * cb.w);
  size_t pb = (size_t)(n >> 3) * 256 + (size_t)c4 * 8 + (n & 7);
  Ph[pb] = (_Float16)xv.x;
  Ph[pb + 8] = (_Float16)xv.y;
  Ph[pb + 16] = (_Float16)xv.z;
  Ph[pb + 24] = (_Float16)xv.w;
}

// t = sum_s part[s]; Pnew = cL*t + cP*Pprev - cPP*Pprev2; y += comb (.) Pnew;
// Ph_blk = fp16(Pnew)
__global__ __launch_bounds__(256) void poly_update(
    const float* __restrict__ part, float* __restrict__ Pnew,
    const float* __restrict__ Pprev, const float* __restrict__ Pprev2,
    float* __restrict__ y, _Float16* __restrict__ Ph, const float* __restrict__ conv,
    const float* __restrict__ comb_row, float r1, float r2, float r3, int ia, int ib,
    int has2) {
  int idx = blockIdx.x * blockDim.x + threadIdx.x;
  float a1 = 2.f * tanhf(conv[ia]);
  float cL = a1 * r1;
  float cP = a1 * r2;

  float4 t = make_float4(0.f, 0.f, 0.f, 0.f);
#pragma unroll
  for (int s = 0; s < NSPLIT; ++s) {
    float4 p = reinterpret_cast<const float4*>(part)[(size_t)s * (NN * CC / 4) + idx];
    t.x += p.x;
    t.y += p.y;
    t.z += p.z;
    t.w += p.w;
  }

  float4 pp = reinterpret_cast<const float4*>(Pprev)[idx];
  float4 pn;
  pn.x = cL * t.x + cP * pp.x;
  pn.y = cL * t.y + cP * pp.y;
  pn.z = cL * t.z + cP * pp.z;
  pn.w = cL * t.w + cP * pp.w;
  if (has2) {
    float a2 = 2.f * tanhf(conv[ib]);
    float cPP = a1 * a2 * r3;
    float4 p2 = reinterpret_cast<const float4*>(Pprev2)[idx];
    pn.x -= cPP * p2.x;
    pn.y -= cPP * p2.y;
    pn.z -= cPP * p2.z;
    pn.w -= cPP * p2.w;
  }
  reinterpret_cast<float4*>(Pnew)[idx] = pn;

  int c4 = (idx & 7) << 2;
  int n = idx >> 3;
  size_t pb = (size_t)(n >> 3) * 256 + (size_t)c4 * 8 + (n & 7);
  Ph[pb] = (_Float16)pn.x;
  Ph[pb + 8] = (_Float16)pn.y;
  Ph[pb + 16] = (_Float16)pn.z;
  Ph[pb + 24] = (_Float16)pn.w;

  float4 cb = *reinterpret_cast<const float4*>(comb_row + c4);
  float4 yv = reinterpret_cast<float4*>(y)[idx];
  yv.x = fmaf(cb.x, pn.x, yv.x);
  yv.y = fmaf(cb.y, pn.y, yv.y);
  yv.z = fmaf(cb.z, pn.z, yv.z);
  yv.w = fmaf(cb.w, pn.w, yv.w);
  reinterpret_cast<float4*>(y)[idx] = yv;
}

// ---------------------------------------------------------------- host side
static void jacobi_r(int i, double a, double b, float& r1, float& r2, float& r3) {
  double div = 2.0 * i * (i + a + b) * (2.0 * i + a + b - 2.0);
  r1 = (float)((2.0 * i + a + b) * (2.0 * i + a + b - 1.0) * (2.0 * i + a + b - 2.0) / div);
  r2 = (float)((2.0 * i + a + b - 1.0) * (a * a - b * b) / div);
  r3 = (float)(2.0 * (i + a - 1.0) * (i + b - 1.0) * (2.0 * i + a + b) / div);
}

extern "C" void kernel_launch(void* const* d_in, const int* in_sizes, int n_in,
                              void* d_out, int out_size, void* d_ws, size_t ws_size,
                              hipStream_t stream) {
  const float* x = (const float*)d_in[0];
  const float* Lm = (const float*)d_in[1];
  const float* conv = (const float*)d_in[2];
  const float* comb = (const float*)d_in[3];
  float* y = (float*)d_out;
  char* ws = (char*)d_ws;

  // workspace layout (bytes)
  _Float16* Lf = (_Float16*)ws;                                 // 512 MiB
  float* part = (float*)(ws + 536870912ull);                    // 32 MiB
  _Float16* Ph = (_Float16*)(ws + 536870912ull + 33554432ull);  // 1 MiB (+pad)
  float* Pb0 = (float*)(ws + 536870912ull + 33554432ull + 2097152ull);
  float* Pb1 = Pb0 + (size_t)NN * CC;
  float* Pb2 = Pb1 + (size_t)NN * CC;
  float* bufs[3] = {Pb0, Pb1, Pb2};

  const double Aj = 1.0, Bj = 1.0;
  const int ew_blocks = NN * CC / 4 / 256;  // 512

  conv_L_pack<<<16384, 256, 0, stream>>>(Lm, Lf);
  init_kernel<<<ew_blocks, 256, 0, stream>>>(x, comb, y, Ph);

  const float* Pprev = x;
  const float* Pprev2 = x;  // unused for i==1
  for (int i = 1; i <= KPOLY; ++i) {
    gemm_f16<<<64 * NSPLIT, 256, 0, stream>>>(Lf, Ph, part);

    float r1, r2, r3;
    if (i == 1) {
      r1 = (float)((Aj + Bj + 2.0) / 2.0);
      r2 = (float)((Aj - Bj) / 2.0);
      r3 = 0.f;
    } else {
      jacobi_r(i, Aj, Bj, r1, r2, r3);
    }
    float* Pn = bufs[(i - 1) % 3];
    poly_update<<<ew_blocks, 256, 0, stream>>>(part, Pn, Pprev, Pprev2, y, Ph, conv,
                                               comb + (size_t)i * CC, r1, r2, r3, i - 1,
                                               (i >= 2) ? i - 2 : 0, (i >= 2) ? 1 : 0);
    Pprev2 = Pprev;
    Pprev = Pn;
  }
}

// Round 6
// 1275.511 us; speedup vs baseline: 26.1075x; 1.0815x over previous
//
#include <hip/hip_runtime.h>
#include <math.h>

// JacobiConv: y = sum_k comb[k] (.) P_k,  P_k = Jacobi recurrence with L @ P matmuls.
// N=16384, C=32, K=10, A=B=1.
// Round 6: fuse GEMM #1 into conv_L_pack (the LDS gather value IS the MFMA
// A-fragment). Saves one full 0.54 GB fp16 L pass. Slab sc == split (NSPLIT=16).
// Order: init_kernel (builds Ph) -> conv_pack_gemm1 -> 9x gemm_f16 + 10x poly_update.

#define NN 16384
#define CC 32
#define KPOLY 10
#define NSPLIT 16
#define KSEG (NN / NSPLIT)   // 1024
#define STEPS (KSEG / 32)    // 32
#define NTK (NN / 32)        // 512 k-tiles per row-block

typedef _Float16 half8 __attribute__((ext_vector_type(8)));
typedef float f32x4 __attribute__((ext_vector_type(4)));
typedef unsigned int u32x4 __attribute__((ext_vector_type(4)));
typedef unsigned int u32x2 __attribute__((ext_vector_type(2)));

union U16 {
  u32x4 u;
  half8 h;
};
union H4 {
  _Float16 h[4];
  u32x2 u;
};

// ---------------------- L fp32 -> fp16 fragment pack, fused with GEMM for P1
// Lf layout: Lf[((tr*NTK + tk)*64 + lane)*8 + pos] =
//            L[tr*16 + (lane&15)][tk*32 + (lane>>4)*8 + pos]
// Block: 16 rows x 1024 cols slab (tr, sc). Phase 1: coalesced fp32 read ->
// swizzled LDS. Phase 2: per-lane 16B LDS gather (= MFMA A-frag) -> coalesced
// 1KB/wave Lf write + 2 MFMAs vs Ph. Phase 3: 4-wave tree reduce -> part[sc].
__global__ __launch_bounds__(256) void conv_pack_gemm1(const float* __restrict__ L,
                                                       _Float16* __restrict__ Lf,
                                                       const _Float16* __restrict__ Ph,
                                                       float* __restrict__ part) {
  __shared__ __align__(16) _Float16 lds[16 * 1024];  // 32 KiB; swizzle u ^= (r&7)
  const int tid = threadIdx.x;
  const int tr = blockIdx.x >> 4;  // row-block 0..1023
  const int sc = blockIdx.x & 15;  // col-slab == split 0..15
  const float* src = L + (size_t)tr * 16 * NN + (size_t)sc * 1024;

#pragma unroll
  for (int j = 0; j < 16; ++j) {
    const int flat = j * 256 + tid;  // 0..4095
    const int r = flat >> 8;         // row 0..15
    const int cu = flat & 255;       // float4 index within row
    f32x4 v = __builtin_nontemporal_load(
        reinterpret_cast<const f32x4*>(src + (size_t)r * NN) + cu);
    H4 o;
    o.h[0] = (_Float16)v.x;
    o.h[1] = (_Float16)v.y;
    o.h[2] = (_Float16)v.z;
    o.h[3] = (_Float16)v.w;
    const int u = (cu >> 1) ^ (r & 7);
    *reinterpret_cast<u32x2*>(&lds[r * 1024 + u * 8 + (cu & 1) * 4]) = o.u;
  }
  __syncthreads();

  const int lane = tid & 63;
  const int wave = tid >> 6;
  const int r = lane & 15;
  const int lg = lane >> 4;

  f32x4 acc0 = (f32x4){0.f, 0.f, 0.f, 0.f};
  f32x4 acc1 = (f32x4){0.f, 0.f, 0.f, 0.f};
#pragma unroll
  for (int i = 0; i < 8; ++i) {
    const int tkl = wave * 8 + i;  // k-tile within slab 0..31
    const int u = (tkl * 4 + lg) ^ (r & 7);
    U16 aval;
    aval.u = *reinterpret_cast<const u32x4*>(&lds[r * 1024 + u * 8]);
    const size_t tk = (size_t)sc * 32 + tkl;
    __builtin_nontemporal_store(
        aval.u, reinterpret_cast<u32x4*>(Lf + ((size_t)tr * NTK + tk) * 512) + lane);
    const int kb = sc * 128 + tkl * 4 + lg;  // 8-elem k-block into Ph
    U16 b0, b1;
    b0.u = *reinterpret_cast<const u32x4*>(Ph + (size_t)kb * 256 + (size_t)r * 8);
    b1.u = *reinterpret_cast<const u32x4*>(Ph + (size_t)kb * 256 + (size_t)(16 + r) * 8);
    acc0 = __builtin_amdgcn_mfma_f32_16x16x32_f16(aval.h, b0.h, acc0, 0, 0, 0);
    acc1 = __builtin_amdgcn_mfma_f32_16x16x32_f16(aval.h, b1.h, acc1, 0, 0, 0);
  }
  __syncthreads();

  float* red = reinterpret_cast<float*>(lds);  // reuse: 4 waves x 512 f32 = 8 KiB
#pragma unroll
  for (int j = 0; j < 4; ++j) {
    red[wave * 512 + (lg * 4 + j) * 32 + r] = acc0[j];
    red[wave * 512 + (lg * 4 + j) * 32 + 16 + r] = acc1[j];
  }
  __syncthreads();

  const int e = tid * 2;  // 256 threads x 2 floats = 512 entries (16 rows x 32 cols)
  float2 s0 = *reinterpret_cast<const float2*>(&red[e]);
  float2 s1 = *reinterpret_cast<const float2*>(&red[512 + e]);
  float2 s2 = *reinterpret_cast<const float2*>(&red[1024 + e]);
  float2 s3 = *reinterpret_cast<const float2*>(&red[1536 + e]);
  float2 s = make_float2(s0.x + s1.x + s2.x + s3.x, s0.y + s1.y + s2.y + s3.y);
  *reinterpret_cast<float2*>(part + (size_t)sc * NN * CC + (size_t)tr * 16 * CC + e) = s;
}

// ------------------------------------------------------------- f16 MFMA GEMM
// part[split][n][c] = sum over k-seg of L[n][k] * P[k][c]
// Grid: 1024 blocks x 256 threads. Block = 4 waves; wave owns 64 rows, one k-seg.
__global__ __launch_bounds__(256, 4) void gemm_f16(const _Float16* __restrict__ Lf,
                                                   const _Float16* __restrict__ Ph,
                                                   float* __restrict__ part) {
  const int tid = threadIdx.x;
  const int lane = tid & 63;
  const int wave = tid >> 6;
  const int rg = blockIdx.x & 63;
  const int split = blockIdx.x >> 6;
  const int rb = rg * 256 + wave * 64;
  const int k0 = split * KSEG;
  const int tk0 = k0 >> 5;
  const int l15 = lane & 15;
  const int lg = lane >> 4;

  const u32x4* Ap[4];
#pragma unroll
  for (int rt = 0; rt < 4; ++rt)
    Ap[rt] = reinterpret_cast<const u32x4*>(
                 Lf + ((size_t)((rb >> 4) + rt) * NTK + tk0) * 512) +
             lane;
  const u32x4* Bp[2];
#pragma unroll
  for (int ct = 0; ct < 2; ++ct)
    Bp[ct] = reinterpret_cast<const u32x4*>(Ph + (size_t)(k0 / 8 + lg) * 256 +
                                            (size_t)(ct * 16 + l15) * 8);

  f32x4 acc[4][2];
#pragma unroll
  for (int rt = 0; rt < 4; ++rt)
#pragma unroll
    for (int ct = 0; ct < 2; ++ct) acc[rt][ct] = (f32x4){0.f, 0.f, 0.f, 0.f};

  U16 A[2][4], B[2][2];
#pragma unroll
  for (int rt = 0; rt < 4; ++rt) A[0][rt].u = __builtin_nontemporal_load(Ap[rt]);
#pragma unroll
  for (int ct = 0; ct < 2; ++ct) B[0][ct].u = *Bp[ct];

#pragma unroll
  for (int kk = 0; kk < STEPS; ++kk) {
    const int cur = kk & 1;
    const int nxt = cur ^ 1;
    if (kk < STEPS - 1) {
#pragma unroll
      for (int rt = 0; rt < 4; ++rt)
        A[nxt][rt].u = __builtin_nontemporal_load(Ap[rt] + (kk + 1) * 64);
#pragma unroll
      for (int ct = 0; ct < 2; ++ct)
        B[nxt][ct].u = *reinterpret_cast<const u32x4*>(
            reinterpret_cast<const _Float16*>(Bp[ct]) + 1024 * (kk + 1));
    }
#pragma unroll
    for (int rt = 0; rt < 4; ++rt)
#pragma unroll
      for (int ct = 0; ct < 2; ++ct)
        acc[rt][ct] = __builtin_amdgcn_mfma_f32_16x16x32_f16(A[cur][rt].h, B[cur][ct].h,
                                                             acc[rt][ct], 0, 0, 0);
  }

  float* pb = part + (size_t)split * NN * CC;
#pragma unroll
  for (int rt = 0; rt < 4; ++rt)
#pragma unroll
    for (int ct = 0; ct < 2; ++ct)
#pragma unroll
      for (int j = 0; j < 4; ++j)
        pb[(size_t)(rb + rt * 16 + lg * 4 + j) * CC + ct * 16 + l15] = acc[rt][ct][j];
}

// ---------------------------------------------------------------- elementwise
// y = comb0 (.) x ; Ph_blk = fp16(x)
__global__ __launch_bounds__(256) void init_kernel(const float* __restrict__ x,
                                                   const float* __restrict__ comb,
                                                   float* __restrict__ y,
                                                   _Float16* __restrict__ Ph) {
  int idx = blockIdx.x * blockDim.x + threadIdx.x;  // float4 index over N*C/4
  float4 xv = reinterpret_cast<const float4*>(x)[idx];
  int c4 = (idx & 7) << 2;
  int n = idx >> 3;
  float4 cb = *reinterpret_cast<const float4*>(comb + c4);
  reinterpret_cast<float4*>(y)[idx] =
      make_float4(xv.x * cb.x, xv.y * cb.y, xv.z * cb.z, xv.w * cb.w);
  size_t pb = (size_t)(n >> 3) * 256 + (size_t)c4 * 8 + (n & 7);
  Ph[pb] = (_Float16)xv.x;
  Ph[pb + 8] = (_Float16)xv.y;
  Ph[pb + 16] = (_Float16)xv.z;
  Ph[pb + 24] = (_Float16)xv.w;
}

// t = sum_s part[s]; Pnew = cL*t + cP*Pprev - cPP*Pprev2; y += comb (.) Pnew;
// Ph_blk = fp16(Pnew)
__global__ __launch_bounds__(256) void poly_update(
    const float* __restrict__ part, float* __restrict__ Pnew,
    const float* __restrict__ Pprev, const float* __restrict__ Pprev2,
    float* __restrict__ y, _Float16* __restrict__ Ph, const float* __restrict__ conv,
    const float* __restrict__ comb_row, float r1, float r2, float r3, int ia, int ib,
    int has2) {
  int idx = blockIdx.x * blockDim.x + threadIdx.x;
  float a1 = 2.f * tanhf(conv[ia]);
  float cL = a1 * r1;
  float cP = a1 * r2;

  float4 t = make_float4(0.f, 0.f, 0.f, 0.f);
#pragma unroll
  for (int s = 0; s < NSPLIT; ++s) {
    float4 p = reinterpret_cast<const float4*>(part)[(size_t)s * (NN * CC / 4) + idx];
    t.x += p.x;
    t.y += p.y;
    t.z += p.z;
    t.w += p.w;
  }

  float4 pp = reinterpret_cast<const float4*>(Pprev)[idx];
  float4 pn;
  pn.x = cL * t.x + cP * pp.x;
  pn.y = cL * t.y + cP * pp.y;
  pn.z = cL * t.z + cP * pp.z;
  pn.w = cL * t.w + cP * pp.w;
  if (has2) {
    float a2 = 2.f * tanhf(conv[ib]);
    float cPP = a1 * a2 * r3;
    float4 p2 = reinterpret_cast<const float4*>(Pprev2)[idx];
    pn.x -= cPP * p2.x;
    pn.y -= cPP * p2.y;
    pn.z -= cPP * p2.z;
    pn.w -= cPP * p2.w;
  }
  reinterpret_cast<float4*>(Pnew)[idx] = pn;

  int c4 = (idx & 7) << 2;
  int n = idx >> 3;
  size_t pb = (size_t)(n >> 3) * 256 + (size_t)c4 * 8 + (n & 7);
  Ph[pb] = (_Float16)pn.x;
  Ph[pb + 8] = (_Float16)pn.y;
  Ph[pb + 16] = (_Float16)pn.z;
  Ph[pb + 24] = (_Float16)pn.w;

  float4 cb = *reinterpret_cast<const float4*>(comb_row + c4);
  float4 yv = reinterpret_cast<float4*>(y)[idx];
  yv.x = fmaf(cb.x, pn.x, yv.x);
  yv.y = fmaf(cb.y, pn.y, yv.y);
  yv.z = fmaf(cb.z, pn.z, yv.z);
  yv.w = fmaf(cb.w, pn.w, yv.w);
  reinterpret_cast<float4*>(y)[idx] = yv;
}

// ---------------------------------------------------------------- host side
static void jacobi_r(int i, double a, double b, float& r1, float& r2, float& r3) {
  double div = 2.0 * i * (i + a + b) * (2.0 * i + a + b - 2.0);
  r1 = (float)((2.0 * i + a + b) * (2.0 * i + a + b - 1.0) * (2.0 * i + a + b - 2.0) / div);
  r2 = (float)((2.0 * i + a + b - 1.0) * (a * a - b * b) / div);
  r3 = (float)(2.0 * (i + a - 1.0) * (i + b - 1.0) * (2.0 * i + a + b) / div);
}

extern "C" void kernel_launch(void* const* d_in, const int* in_sizes, int n_in,
                              void* d_out, int out_size, void* d_ws, size_t ws_size,
                              hipStream_t stream) {
  const float* x = (const float*)d_in[0];
  const float* Lm = (const float*)d_in[1];
  const float* conv = (const float*)d_in[2];
  const float* comb = (const float*)d_in[3];
  float* y = (float*)d_out;
  char* ws = (char*)d_ws;

  // workspace layout (bytes)
  _Float16* Lf = (_Float16*)ws;                                 // 512 MiB
  float* part = (float*)(ws + 536870912ull);                    // 32 MiB
  _Float16* Ph = (_Float16*)(ws + 536870912ull + 33554432ull);  // 1 MiB (+pad)
  float* Pb0 = (float*)(ws + 536870912ull + 33554432ull + 2097152ull);
  float* Pb1 = Pb0 + (size_t)NN * CC;
  float* Pb2 = Pb1 + (size_t)NN * CC;
  float* bufs[3] = {Pb0, Pb1, Pb2};

  const double Aj = 1.0, Bj = 1.0;
  const int ew_blocks = NN * CC / 4 / 256;  // 512

  init_kernel<<<ew_blocks, 256, 0, stream>>>(x, comb, y, Ph);  // Ph before fused conv
  conv_pack_gemm1<<<16384, 256, 0, stream>>>(Lm, Lf, Ph, part);

  const float* Pprev = x;
  const float* Pprev2 = x;  // unused for i==1
  for (int i = 1; i <= KPOLY; ++i) {
    if (i > 1) gemm_f16<<<64 * NSPLIT, 256, 0, stream>>>(Lf, Ph, part);

    float r1, r2, r3;
    if (i == 1) {
      r1 = (float)((Aj + Bj + 2.0) / 2.0);
      r2 = (float)((Aj - Bj) / 2.0);
      r3 = 0.f;
    } else {
      jacobi_r(i, Aj, Bj, r1, r2, r3);
    }
    float* Pn = bufs[(i - 1) % 3];
    poly_update<<<ew_blocks, 256, 0, stream>>>(part, Pn, Pprev, Pprev2, y, Ph, conv,
                                               comb + (size_t)i * CC, r1, r2, r3, i - 1,
                                               (i >= 2) ? i - 2 : 0, (i >= 2) ? 1 : 0);
    Pprev2 = Pprev;
    Pprev = Pn;
  }
}